// Round 5
// baseline (205.245 us; speedup 1.0000x reference)
//
#include <hip/hip_runtime.h>

// DCN: B=4, C=64, H=W=128, Cout=64, 3x3, pad=1, stride=1, dil=1
#define B_   4
#define C_   64
#define H_   128
#define W_   128
#define OC_  64
#define K_   9
#define OCH_ 18
#define CK_  576

#define S_    104            // Pl row stride in halfs (208 B, 16B-aligned)
#define WCOLS 768            // 8 chunks * 96 padded cols
#define XSW   72             // x window cols (64 + 2*4 halo)
#define XSH   9              // x window rows (ho-4 .. ho+4)
#define XSC   (XSH*XSW)      // 648 floats per channel

#define WPAD_HALFS (OC_*WCOLS)   // 49152

using half8v  = __attribute__((ext_vector_type(8))) _Float16;
using half2v  = __attribute__((ext_vector_type(2))) _Float16;
using float4v = __attribute__((ext_vector_type(4))) float;

// ---------------------------------------------------------------------------
// k0: cast+pad weights to f16 in MFMA-chunk layout.
// col = cc*96 + kk*8 + cl  (channel c = cc*8+cl, tap kk; kk>=9 -> 0)
// ---------------------------------------------------------------------------
__global__ void k0_prep(const float* __restrict__ w, const float* __restrict__ ow,
                        _Float16* __restrict__ wpad, _Float16* __restrict__ w0pad) {
    int i = blockIdx.x * 256 + threadIdx.x;
    if (i < OC_ * WCOLS) {
        int oc = i / WCOLS, col = i - oc * WCOLS;
        int cc = col / 96, r = col - cc * 96;
        int kk = r >> 3, cl = r & 7;
        float v = 0.f;
        if (kk < 9) v = w[oc * CK_ + (cc * 8 + cl) * 9 + kk];
        wpad[i] = (_Float16)v;
    } else {
        int j = i - OC_ * WCOLS;
        if (j < 32 * WCOLS) {
            int rr = j / WCOLS, col = j - rr * WCOLS;
            int cc = col / 96, r = col - cc * 96;
            int kk = r >> 3, cl = r & 7;
            float v = 0.f;
            if (rr < OCH_ && kk < 9) v = ow[rr * CK_ + (cc * 8 + cl) * 9 + kk];
            w0pad[j] = (_Float16)v;
        }
    }
}

// ---------------------------------------------------------------------------
// k_fused: register-pipelined.  Per chunk: sync(a); issue next-chunk global
// loads into regs; compute from LDS; sync(b); MFMA; write regs->LDS.
// Sampling ownership: wave w owns pixels [w*16,w*16+16), thread=(lr=pixel,
// q=channel-pair) -> Pl write banks (52*lr+4kk+q)%32 are conflict-free.
// LDS 38.7 KB -> 4 blocks/CU.
// ---------------------------------------------------------------------------
__global__ __launch_bounds__(256, 4) void k_fused(
    const float* __restrict__ x, const _Float16* __restrict__ wpad,
    const _Float16* __restrict__ w0pad, const float* __restrict__ bias,
    const float* __restrict__ ob, float* __restrict__ out)
{
    __shared__ __align__(16) float    xs[8 * XSC];   // 20736 B
    __shared__ __align__(16) _Float16 Pl[64 * S_];   // 13312 B
    __shared__ float offs_lds[OCH_ * 64];            //  4608 B

    // ---- XCD-aware work decode ----
    const int g   = blockIdx.x;
    const int xcd = g & 7;
    const int n   = g >> 3;
    const int hb  = n & 1;
    const int hol = (n >> 1) & 15;
    const int b   = n >> 5;
    const int ho  = xcd * 16 + hol;

    const int t = threadIdx.x, lane = t & 63, w = t >> 6;
    const int lr = lane & 15, q = lane >> 4;
    const int lpix = w * 16 + lr;            // this thread's local pixel
    const int po   = hb * 64 + lpix;         // global pixel column
    const int start = hb * 64 - 4;
    const float* xb = x + ((long)b << 20);

    // zero Pl pad cols 72..95 once
    for (int i = t; i < 64 * 12; i += 256) {
        int row = i / 12, j = i - row * 12;
        *(unsigned*)&Pl[row * S_ + 72 + 2 * j] = 0u;
    }

    // ---- staging slot descriptors (decoded once) ----
    // phase1: window rows 3..5 only (432 float4)
    int  v1xo[2], v1lo[2]; bool v1ok[2], v1v[2];
#pragma unroll
    for (int s = 0; s < 2; s++) {
        int idx = t + 256 * s;
        v1v[s] = idx < 432;
        int ii = v1v[s] ? idx : 0;
        int c  = ii / 54, rj = ii - c * 54;
        int r3 = rj / 18, jc = rj - r3 * 18;
        int gy = ho - 1 + r3, gx = start + 4 * jc;
        v1ok[s] = ((unsigned)gy < (unsigned)H_) && (gx >= 0) && (gx + 3 < W_);
        v1xo[s] = (c << 14) + (gy << 7) + gx;
        v1lo[s] = c * XSC + (3 + r3) * XSW + 4 * jc;
    }
    // phase2: full 9-row window (1296 float4)
    int  v2xo[6], v2lo[6]; bool v2ok[6], v2v[6];
#pragma unroll
    for (int s = 0; s < 6; s++) {
        int idx = t + 256 * s;
        v2v[s] = idx < 1296;
        int ii = v2v[s] ? idx : 0;
        int c  = ii / 162, rj = ii - c * 162;
        int r  = rj / 18, jc = rj - r * 18;
        int gy = ho - 4 + r, gx = start + 4 * jc;
        v2ok[s] = ((unsigned)gy < (unsigned)H_) && (gx >= 0) && (gx + 3 < W_);
        v2xo[s] = (c << 14) + (gy << 7) + gx;
        v2lo[s] = c * XSC + r * XSW + 4 * jc;
    }

    // ================= phase 1: offset conv =================
    // preamble: stage chunk 0 rows
#pragma unroll
    for (int s = 0; s < 2; s++) if (v1v[s]) {
        float4v vv = {0.f, 0.f, 0.f, 0.f};
        if (v1ok[s]) vv = *(const float4v*)(xb + v1xo[s]);
        *(float4v*)&xs[v1lo[s]] = vv;
    }

    float4v oa0 = {0.f,0.f,0.f,0.f}, oa1 = {0.f,0.f,0.f,0.f};
    const int sxb = lpix + 3;                // tap col base in window

    for (int cc = 0; cc < 8; cc++) {
        __syncthreads();                     // (a) xs ready
        // prefetch next chunk rows into regs (drained at sync b)
        float4v n1[2];
#pragma unroll
        for (int s = 0; s < 2; s++) {
            n1[s] = (float4v){0.f, 0.f, 0.f, 0.f};
            if (cc < 7 && v1v[s] && v1ok[s])
                n1[s] = *(const float4v*)(xb + ((cc + 1) << 17) + v1xo[s]);
        }
        // im2col from LDS window: channels 2q, 2q+1, pixel lpix
        {
            const float* b0 = xs + (2 * q) * XSC;
            const float* b1 = b0 + XSC;
#pragma unroll
            for (int ky = 0; ky < 3; ky++) {
#pragma unroll
                for (int kx = 0; kx < 3; kx++) {
                    float u0 = b0[(3 + ky) * XSW + sxb + kx];
                    float u1 = b1[(3 + ky) * XSW + sxb + kx];
                    half2v hv = {(_Float16)u0, (_Float16)u1};
                    *(half2v*)&Pl[lpix * S_ + (ky * 3 + kx) * 8 + 2 * q] = hv;
                }
            }
        }
        __syncthreads();                     // (b) Pl ready
#pragma unroll
        for (int ks = 0; ks < 3; ks++) {
            half8v a0 = *(const half8v*)&w0pad[lr * WCOLS + cc * 96 + ks * 32 + q * 8];
            half8v a1 = *(const half8v*)&w0pad[(16 + lr) * WCOLS + cc * 96 + ks * 32 + q * 8];
            half8v bv = *(const half8v*)&Pl[(w * 16 + lr) * S_ + ks * 32 + q * 8];
            oa0 = __builtin_amdgcn_mfma_f32_16x16x32_f16(a0, bv, oa0, 0, 0, 0);
            oa1 = __builtin_amdgcn_mfma_f32_16x16x32_f16(a1, bv, oa1, 0, 0, 0);
        }
        if (cc < 7) {
#pragma unroll
            for (int s = 0; s < 2; s++) if (v1v[s])
                *(float4v*)&xs[v1lo[s]] = n1[s];
        }
    }

    // offsets -> LDS
    {
#pragma unroll
        for (int r = 0; r < 4; r++) {
            int ch = q * 4 + r;
            offs_lds[ch * 64 + lpix] = oa0[r] + ob[ch];
        }
#pragma unroll
        for (int r = 0; r < 4; r++) {
            int ch = 16 + q * 4 + r;
            if (ch < OCH_) offs_lds[ch * 64 + lpix] = oa1[r] + ob[ch];
        }
    }
    __syncthreads();

    // ============ phase2 preamble: issue chunk-0 loads, meta, stage ========
    float4v m2[6];
#pragma unroll
    for (int s = 0; s < 6; s++) {
        m2[s] = (float4v){0.f, 0.f, 0.f, 0.f};
        if (v2v[s] && v2ok[s]) m2[s] = *(const float4v*)(xb + v2xo[s]);
    }
    // bilinear meta (overlaps load latency)
    unsigned moff[9];
    half2v   mwa[9], mwb[9];
    unsigned okm = 0;
#pragma unroll
    for (int kk = 0; kk < 9; kk++) {
        int ky = kk / 3, kx = kk - 3 * ky;
        float dy = offs_lds[(2 * kk) * 64 + lpix];
        float dx = offs_lds[(2 * kk + 1) * 64 + lpix];
        float py = (float)(ho - 1 + ky) + dy;
        float px = (float)(po - 1 + kx) + dx;
        float fy = floorf(py), fx = floorf(px);
        float ly = py - fy, lx = px - fx;
        int y0 = (int)fy, x0 = (int)fx;
        int y1 = y0 + 1, x1 = x0 + 1;
        float vy0 = ((unsigned)y0 < (unsigned)H_) ? 1.f : 0.f;
        float vy1 = ((unsigned)y1 < (unsigned)H_) ? 1.f : 0.f;
        float vx0 = ((unsigned)x0 < (unsigned)W_) ? 1.f : 0.f;
        float vx1 = ((unsigned)x1 < (unsigned)W_) ? 1.f : 0.f;
        float w00 = (1.f - ly) * (1.f - lx) * vy0 * vx0;
        float w01 = (1.f - ly) * lx * vy0 * vx1;
        float w10 = ly * (1.f - lx) * vy1 * vx0;
        float w11 = ly * lx * vy1 * vx1;
        int cy0 = min(max(y0, 0), H_ - 1);
        int cy1 = min(max(y1, 0), H_ - 1);
        int xl  = min(max(x0, 0), W_ - 2);
        bool noswap = (x0 == xl);            // fold x-clamp into weight swap
        float a = noswap ? w00 : w01, bb = noswap ? w01 : w00;
        float c = noswap ? w10 : w11, d  = noswap ? w11 : w10;
        mwa[kk] = {(_Float16)a, (_Float16)bb};
        mwb[kk] = {(_Float16)c, (_Float16)d};
        int sy0 = cy0 - (ho - 4);
        int sy1 = cy1 - (ho - 4);
        int sx  = xl - start;
        bool ok = ((unsigned)sy0 < (unsigned)XSH) && ((unsigned)sy1 < (unsigned)XSH)
               && ((unsigned)sx < (unsigned)(XSW - 1));
        okm |= (ok ? 1u : 0u) << kk;
        moff[kk] = (unsigned)(sy0 * XSW + sx) | ((unsigned)(sy1 * XSW + sx) << 16);
    }
    // stage chunk 0 window
#pragma unroll
    for (int s = 0; s < 6; s++) if (v2v[s]) *(float4v*)&xs[v2lo[s]] = m2[s];

    // ================= phase 2: sample + main conv =================
    float4v a00 = {0.f,0.f,0.f,0.f}, a01 = {0.f,0.f,0.f,0.f};
    float4v a10 = {0.f,0.f,0.f,0.f}, a11 = {0.f,0.f,0.f,0.f};
    const int wm = w & 1, wn = w >> 1;

    for (int cc = 0; cc < 8; cc++) {
        __syncthreads();                     // (a) xs ready
        // prefetch next chunk window into regs (drained at sync b)
        float4v nx[6];
#pragma unroll
        for (int s = 0; s < 6; s++) {
            nx[s] = (float4v){0.f, 0.f, 0.f, 0.f};
            if (cc < 7 && v2v[s] && v2ok[s])
                nx[s] = *(const float4v*)(xb + ((cc + 1) << 17) + v2xo[s]);
        }
        // sample channels 2q, 2q+1 at pixel lpix
        const float* xs0 = xs + (2 * q) * XSC;
        const float* xs1 = xs0 + XSC;
        float p0[9], p1[9];
        if (__all(okm == 0x1FFu)) {
#pragma unroll
            for (int kk = 0; kk < 9; kk++) {
                int A  = (int)(moff[kk] & 0xFFFFu);
                int Bo = (int)(moff[kk] >> 16);
                float u0 = (float)mwa[kk][0], u1 = (float)mwa[kk][1];
                float u2 = (float)mwb[kk][0], u3 = (float)mwb[kk][1];
                p0[kk] = xs0[A] * u0 + xs0[A + 1] * u1 + xs0[Bo] * u2 + xs0[Bo + 1] * u3;
                p1[kk] = xs1[A] * u0 + xs1[A + 1] * u1 + xs1[Bo] * u2 + xs1[Bo + 1] * u3;
            }
        } else {
            // rare: recompute, gather from global (clamped, valid)
            const float* xc0 = xb + ((long)(cc * 8 + 2 * q) << 14);
            const float* xc1 = xc0 + (1 << 14);
#pragma unroll
            for (int kk = 0; kk < 9; kk++) {
                int ky = kk / 3, kx = kk - 3 * ky;
                float dy = offs_lds[(2 * kk) * 64 + lpix];
                float dx = offs_lds[(2 * kk + 1) * 64 + lpix];
                float py = (float)(ho - 1 + ky) + dy;
                float px = (float)(po - 1 + kx) + dx;
                int y0 = (int)floorf(py), x0 = (int)floorf(px);
                int cy0 = min(max(y0, 0), H_ - 1);
                int cy1 = min(max(y0 + 1, 0), H_ - 1);
                int xl  = min(max(x0, 0), W_ - 2);
                int ga = (cy0 << 7) + xl, gb = (cy1 << 7) + xl;
                float u0 = (float)mwa[kk][0], u1 = (float)mwa[kk][1];
                float u2 = (float)mwb[kk][0], u3 = (float)mwb[kk][1];
                p0[kk] = xc0[ga] * u0 + xc0[ga + 1] * u1 + xc0[gb] * u2 + xc0[gb + 1] * u3;
                p1[kk] = xc1[ga] * u0 + xc1[ga + 1] * u1 + xc1[gb] * u2 + xc1[gb + 1] * u3;
            }
        }
#pragma unroll
        for (int kk = 0; kk < 9; kk++) {
            half2v hv = {(_Float16)p0[kk], (_Float16)p1[kk]};
            *(half2v*)&Pl[lpix * S_ + kk * 8 + 2 * q] = hv;   // conflict-free banks
        }
        __syncthreads();                     // (b) Pl ready; prefetch drained here
#pragma unroll
        for (int ks = 0; ks < 3; ks++) {
            half8v A0 = *(const half8v*)&wpad[(wm * 32 + lr) * WCOLS + cc * 96 + ks * 32 + q * 8];
            half8v A1 = *(const half8v*)&wpad[(wm * 32 + 16 + lr) * WCOLS + cc * 96 + ks * 32 + q * 8];
            half8v B0 = *(const half8v*)&Pl[(wn * 32 + lr) * S_ + ks * 32 + q * 8];
            half8v B1 = *(const half8v*)&Pl[(wn * 32 + 16 + lr) * S_ + ks * 32 + q * 8];
            a00 = __builtin_amdgcn_mfma_f32_16x16x32_f16(A0, B0, a00, 0, 0, 0);
            a01 = __builtin_amdgcn_mfma_f32_16x16x32_f16(A0, B1, a01, 0, 0, 0);
            a10 = __builtin_amdgcn_mfma_f32_16x16x32_f16(A1, B0, a10, 0, 0, 0);
            a11 = __builtin_amdgcn_mfma_f32_16x16x32_f16(A1, B1, a11, 0, 0, 0);
        }
        if (cc < 7) {
#pragma unroll
            for (int s = 0; s < 6; s++) if (v2v[s])
                *(float4v*)&xs[v2lo[s]] = nx[s];
        }
    }

    // ---- epilogue ----
    const int pixc = hb * 64 + wn * 32 + lr;
#pragma unroll
    for (int r = 0; r < 4; r++) {
        int oc0 = wm * 32 + q * 4 + r;
        int oc1 = oc0 + 16;
        float* o0 = out + (((long)(b * OC_ + oc0)) << 14) + (ho << 7);
        float* o1 = out + (((long)(b * OC_ + oc1)) << 14) + (ho << 7);
        o0[pixc]      = a00[r] + bias[oc0];
        o0[pixc + 16] = a01[r] + bias[oc0];
        o1[pixc]      = a10[r] + bias[oc1];
        o1[pixc + 16] = a11[r] + bias[oc1];
    }
}

// ---------------------------------------------------------------------------
extern "C" void kernel_launch(void* const* d_in, const int* in_sizes, int n_in,
                              void* d_out, int out_size, void* d_ws, size_t ws_size,
                              hipStream_t stream) {
    const float* x  = (const float*)d_in[0];
    const float* wt = (const float*)d_in[1];
    const float* bi = (const float*)d_in[2];
    const float* ow = (const float*)d_in[3];
    const float* ob = (const float*)d_in[4];
    float* out = (float*)d_out;

    _Float16* wpad  = (_Float16*)d_ws;
    _Float16* w0pad = wpad + WPAD_HALFS;

    k0_prep<<<(OC_ * WCOLS + 32 * WCOLS + 255) / 256, 256, 0, stream>>>(wt, ow, wpad, w0pad);
    k_fused<<<B_ * H_ * 2, 256, 0, stream>>>(x, wpad, w0pad, bi, ob, out);
}

// Round 6
// 152.482 us; speedup vs baseline: 1.3460x; 1.3460x over previous
//
#include <hip/hip_runtime.h>

// DCN: B=4, C=64, H=W=128, Cout=64, 3x3, pad=1, stride=1, dil=1
#define B_   4
#define C_   64
#define H_   128
#define W_   128
#define OC_  64
#define K_   9
#define OCH_ 18
#define CK_  576

#define S_    104            // Pl row stride in halfs (208 B, 16B-aligned)
#define WCOLS 768            // 8 chunks * 96 padded cols
#define XSW   72             // window cols (64 + 2*4 halo)
#define XSH   7              // window rows (ho-3 .. ho+3)
#define XSC   (XSH*XSW)      // 504 floats per channel (phase-2 layout)
#define XSC1  (3*XSW)        // 216 floats per channel (phase-1 dense layout)
#define XSB   4096           // floats per staging buffer (16 KB, lane-overrun pad)
#define NS2   1008           // 8ch*7row*18 float4 slots
#define NS1   432            // 8ch*3row*18 float4 slots

#define WPAD_HALFS  (OC_*WCOLS)              // 49152
#define W0PAD_HALFS (32*WCOLS)               // 24576
#define ZPAGE_BYTE  (2*WPAD_HALFS + 2*W0PAD_HALFS)   // 147456 (16B aligned)

using half8v  = __attribute__((ext_vector_type(8))) _Float16;
using half2v  = __attribute__((ext_vector_type(2))) _Float16;
using float4v = __attribute__((ext_vector_type(4))) float;

// async 16B global->LDS DMA (no VGPR round-trip; drained by vmcnt at barriers)
#define GLDS16(SRC, DST)                                              \
    __builtin_amdgcn_global_load_lds(                                 \
        (__attribute__((address_space(1))) void*)(SRC),               \
        (__attribute__((address_space(3))) void*)(DST), 16, 0, 0)

// ---------------------------------------------------------------------------
// k0: cast+pad weights to f16 in MFMA-chunk layout; zero the OOB page.
// col = cc*96 + kk*8 + cl  (channel c = cc*8+cl, tap kk; kk>=9 -> 0)
// ---------------------------------------------------------------------------
__global__ void k0_prep(const float* __restrict__ w, const float* __restrict__ ow,
                        _Float16* __restrict__ wpad, _Float16* __restrict__ w0pad,
                        float* __restrict__ zp) {
    if (blockIdx.x == 0 && threadIdx.x < 64) zp[threadIdx.x] = 0.f;
    int i = blockIdx.x * 256 + threadIdx.x;
    if (i < OC_ * WCOLS) {
        int oc = i / WCOLS, col = i - oc * WCOLS;
        int cc = col / 96, r = col - cc * 96;
        int kk = r >> 3, cl = r & 7;
        float v = 0.f;
        if (kk < 9) v = w[oc * CK_ + (cc * 8 + cl) * 9 + kk];
        wpad[i] = (_Float16)v;
    } else {
        int j = i - OC_ * WCOLS;
        if (j < 32 * WCOLS) {
            int rr = j / WCOLS, col = j - rr * WCOLS;
            int cc = col / 96, r = col - cc * 96;
            int kk = r >> 3, cl = r & 7;
            float v = 0.f;
            if (rr < OCH_ && kk < 9) v = ow[rr * CK_ + (cc * 8 + cl) * 9 + kk];
            w0pad[j] = (_Float16)v;
        }
    }
}

// ---------------------------------------------------------------------------
// k_fused: DMA-double-buffered window staging (global_load_lds x16B) +
// phase1 offset conv (im2col from LDS window, MFMA) -> offs in LDS ->
// phase2 bilinear sample from LDS window + main-conv MFMA.
// Block = 64 oc x 64 pix.  LDS 50688 B -> 3 blocks/CU.
// ---------------------------------------------------------------------------
__global__ __launch_bounds__(256, 3) void k_fused(
    const float* __restrict__ x, const _Float16* __restrict__ wpad,
    const _Float16* __restrict__ w0pad, const float* __restrict__ bias,
    const float* __restrict__ ob, const float* __restrict__ zp,
    float* __restrict__ out)
{
    __shared__ __align__(16) float    xs[2 * XSB];   // 32768 B (two DMA buffers)
    __shared__ __align__(16) _Float16 Pl[64 * S_];   // 13312 B
    __shared__ float offs_lds[OCH_ * 64];            //  4608 B

    // ---- XCD-aware work decode ----
    const int g   = blockIdx.x;
    const int xcd = g & 7;
    const int n   = g >> 3;
    const int hb  = n & 1;
    const int hol = (n >> 1) & 15;
    const int b   = n >> 5;
    const int ho  = xcd * 16 + hol;

    const int t = threadIdx.x, lane = t & 63, w = t >> 6;
    const int lr = lane & 15, q = lane >> 4;
    const int lpix = w * 16 + lr;            // this thread's pixel
    const int po   = hb * 64 + lpix;
    const int start = hb * 64 - 4;
    const float* xb = x + ((long)b << 20);

    // zero Pl pad cols 72..95 once
    for (int i = t; i < 64 * 12; i += 256) {
        int row = i / 12, j = i - row * 12;
        *(unsigned*)&Pl[row * S_ + 72 + 2 * j] = 0u;
    }

    // ---- staging slot descriptors (decoded once) ----
    // phase-1: rows ho-1..ho+1, dense 3-row layout (432 slots, 2/thread)
    int g1o[2]; bool g1k[2], g1v[2];
#pragma unroll
    for (int s = 0; s < 2; s++) {
        int idx = t + 256 * s;
        g1v[s] = idx < NS1;
        int ii = g1v[s] ? idx : 0;
        int c  = ii / 54, rj = ii - c * 54;
        int r3 = rj / 18, jc = rj - r3 * 18;
        int gy = ho - 1 + r3, gx = start + 4 * jc;
        g1k[s] = ((unsigned)gy < (unsigned)H_) && (gx >= 0) && (gx + 3 < W_);
        g1o[s] = (c << 14) + (gy << 7) + gx;
    }
    // phase-2: rows ho-3..ho+3, full 7-row layout (1008 slots, 4/thread)
    int g2o[4]; bool g2k[4], g2v[4];
#pragma unroll
    for (int s = 0; s < 4; s++) {
        int idx = t + 256 * s;
        g2v[s] = idx < NS2;
        int ii = g2v[s] ? idx : 0;
        int c  = ii / 126, rj = ii - c * 126;
        int r  = rj / 18, jc = rj - r * 18;
        int gy = ho - 3 + r, gx = start + 4 * jc;
        g2k[s] = ((unsigned)gy < (unsigned)H_) && (gx >= 0) && (gx + 3 < W_);
        g2o[s] = (c << 14) + (gy << 7) + gx;
    }

    // ================= phase 1: offset conv =================
    // prologue: stage chunk 0 (async DMA into buf0)
#pragma unroll
    for (int s = 0; s < 2; s++) if (g1v[s])
        GLDS16(g1k[s] ? (xb + g1o[s]) : zp, xs + 4 * (t + 256 * s));

    float4v oa0 = {0.f,0.f,0.f,0.f}, oa1 = {0.f,0.f,0.f,0.f};

    for (int cc = 0; cc < 8; cc++) {
        __syncthreads();                       // (A) buf[cc&1] ready (drains DMA)
        if (cc < 7) {
            float* dst = xs + ((cc + 1) & 1) * XSB;
            const float* srcb = xb + ((long)(cc + 1) << 17);
#pragma unroll
            for (int s = 0; s < 2; s++) if (g1v[s])
                GLDS16(g1k[s] ? (srcb + g1o[s]) : zp, dst + 4 * (t + 256 * s));
        }
        // im2col from LDS window: channels 2q, 2q+1 at pixel lpix
        {
            const float* b0 = xs + (cc & 1) * XSB + (2 * q) * XSC1;
            const float* b1 = b0 + XSC1;
#pragma unroll
            for (int ky = 0; ky < 3; ky++) {
#pragma unroll
                for (int kx = 0; kx < 3; kx++) {
                    float u0 = b0[ky * XSW + lpix + 3 + kx];
                    float u1 = b1[ky * XSW + lpix + 3 + kx];
                    half2v hv = {(_Float16)u0, (_Float16)u1};
                    *(half2v*)&Pl[lpix * S_ + (ky * 3 + kx) * 8 + 2 * q] = hv;
                }
            }
        }
        __syncthreads();                       // (B) Pl ready (also drains stage cc+1)
#pragma unroll
        for (int ks = 0; ks < 3; ks++) {
            half8v a0 = *(const half8v*)&w0pad[lr * WCOLS + cc * 96 + ks * 32 + q * 8];
            half8v a1 = *(const half8v*)&w0pad[(16 + lr) * WCOLS + cc * 96 + ks * 32 + q * 8];
            half8v bv = *(const half8v*)&Pl[lpix * S_ + ks * 32 + q * 8];
            oa0 = __builtin_amdgcn_mfma_f32_16x16x32_f16(a0, bv, oa0, 0, 0, 0);
            oa1 = __builtin_amdgcn_mfma_f32_16x16x32_f16(a1, bv, oa1, 0, 0, 0);
        }
    }

    // offsets -> LDS
#pragma unroll
    for (int r = 0; r < 4; r++) {
        int ch = q * 4 + r;
        offs_lds[ch * 64 + lpix] = oa0[r] + ob[ch];
    }
#pragma unroll
    for (int r = 0; r < 4; r++) {
        int ch = 16 + q * 4 + r;
        if (ch < OCH_) offs_lds[ch * 64 + lpix] = oa1[r] + ob[ch];
    }
    __syncthreads();                           // (C) offs ready

    // phase-2 prologue: issue chunk-0 DMA, then meta (overlaps DMA latency)
#pragma unroll
    for (int s = 0; s < 4; s++) if (g2v[s])
        GLDS16(g2k[s] ? (xb + g2o[s]) : zp, xs + 4 * (t + 256 * s));

    unsigned moff[9];
    float mw0[9], mw1[9], mw2[9], mw3[9];
    unsigned okm = 0;
#pragma unroll
    for (int kk = 0; kk < 9; kk++) {
        int ky = kk / 3, kx = kk - 3 * ky;
        float dy = offs_lds[(2 * kk) * 64 + lpix];
        float dx = offs_lds[(2 * kk + 1) * 64 + lpix];
        float py = (float)(ho - 1 + ky) + dy;
        float px = (float)(po - 1 + kx) + dx;
        float fy = floorf(py), fx = floorf(px);
        float ly = py - fy, lx = px - fx;
        int y0 = (int)fy, x0 = (int)fx;
        int y1 = y0 + 1, x1 = x0 + 1;
        float vy0 = ((unsigned)y0 < (unsigned)H_) ? 1.f : 0.f;
        float vy1 = ((unsigned)y1 < (unsigned)H_) ? 1.f : 0.f;
        float vx0 = ((unsigned)x0 < (unsigned)W_) ? 1.f : 0.f;
        float vx1 = ((unsigned)x1 < (unsigned)W_) ? 1.f : 0.f;
        float w00 = (1.f - ly) * (1.f - lx) * vy0 * vx0;
        float w01 = (1.f - ly) * lx * vy0 * vx1;
        float w10 = ly * (1.f - lx) * vy1 * vx0;
        float w11 = ly * lx * vy1 * vx1;
        int cy0 = min(max(y0, 0), H_ - 1);
        int cy1 = min(max(y1, 0), H_ - 1);
        int xl  = min(max(x0, 0), W_ - 2);
        bool noswap = (x0 == xl);              // fold x-clamp into weight swap
        mw0[kk] = noswap ? w00 : w01;
        mw1[kk] = noswap ? w01 : w00;
        mw2[kk] = noswap ? w10 : w11;
        mw3[kk] = noswap ? w11 : w10;
        int sy0 = cy0 - (ho - 3);
        int sy1 = cy1 - (ho - 3);
        int sx  = xl - start;
        bool ok = ((unsigned)sy0 < (unsigned)XSH) && ((unsigned)sy1 < (unsigned)XSH)
               && ((unsigned)sx < (unsigned)(XSW - 1));
        okm |= (ok ? 1u : 0u) << kk;
        moff[kk] = (unsigned)(sy0 * XSW + sx) | ((unsigned)(sy1 * XSW + sx) << 16);
    }

    // ================= phase 2: sample + main conv =================
    float4v a00 = {0.f,0.f,0.f,0.f}, a01 = {0.f,0.f,0.f,0.f};
    float4v a10 = {0.f,0.f,0.f,0.f}, a11 = {0.f,0.f,0.f,0.f};
    const int wm = w & 1, wn = w >> 1;

    for (int cc = 0; cc < 8; cc++) {
        __syncthreads();                       // (A) buf[cc&1] ready (drains DMA)
        if (cc < 7) {
            float* dst = xs + ((cc + 1) & 1) * XSB;
            const float* srcb = xb + ((long)(cc + 1) << 17);
#pragma unroll
            for (int s = 0; s < 4; s++) if (g2v[s])
                GLDS16(g2k[s] ? (srcb + g2o[s]) : zp, dst + 4 * (t + 256 * s));
        }
        // sample channels 2q, 2q+1 at pixel lpix
        const float* xs0 = xs + (cc & 1) * XSB + (2 * q) * XSC;
        const float* xs1 = xs0 + XSC;
        if (__all(okm == 0x1FFu)) {
#pragma unroll
            for (int kk = 0; kk < 9; kk++) {
                int A  = (int)(moff[kk] & 0xFFFFu);
                int Bo = (int)(moff[kk] >> 16);
                float p0 = xs0[A] * mw0[kk] + xs0[A + 1] * mw1[kk]
                         + xs0[Bo] * mw2[kk] + xs0[Bo + 1] * mw3[kk];
                float p1 = xs1[A] * mw0[kk] + xs1[A + 1] * mw1[kk]
                         + xs1[Bo] * mw2[kk] + xs1[Bo + 1] * mw3[kk];
                half2v hv = {(_Float16)p0, (_Float16)p1};
                *(half2v*)&Pl[lpix * S_ + kk * 8 + 2 * q] = hv;
            }
        } else {
            // rare big-offset fallback: gather from global (clamped, valid)
            const float* xc0 = xb + ((long)(cc * 8 + 2 * q) << 14);
            const float* xc1 = xc0 + (1 << 14);
#pragma unroll
            for (int kk = 0; kk < 9; kk++) {
                int ky = kk / 3, kx = kk - 3 * ky;
                float dy = offs_lds[(2 * kk) * 64 + lpix];
                float dx = offs_lds[(2 * kk + 1) * 64 + lpix];
                float py = (float)(ho - 1 + ky) + dy;
                float px = (float)(po - 1 + kx) + dx;
                int y0 = (int)floorf(py), x0 = (int)floorf(px);
                int cy0 = min(max(y0, 0), H_ - 1);
                int cy1 = min(max(y0 + 1, 0), H_ - 1);
                int xl  = min(max(x0, 0), W_ - 2);
                int ga = (cy0 << 7) + xl, gb = (cy1 << 7) + xl;
                float p0 = xc0[ga] * mw0[kk] + xc0[ga + 1] * mw1[kk]
                         + xc0[gb] * mw2[kk] + xc0[gb + 1] * mw3[kk];
                float p1 = xc1[ga] * mw0[kk] + xc1[ga + 1] * mw1[kk]
                         + xc1[gb] * mw2[kk] + xc1[gb + 1] * mw3[kk];
                half2v hv = {(_Float16)p0, (_Float16)p1};
                *(half2v*)&Pl[lpix * S_ + kk * 8 + 2 * q] = hv;
            }
        }
        __syncthreads();                       // (B) Pl ready (drains stage cc+1)
#pragma unroll
        for (int ks = 0; ks < 3; ks++) {
            half8v A0 = *(const half8v*)&wpad[(wm * 32 + lr) * WCOLS + cc * 96 + ks * 32 + q * 8];
            half8v A1 = *(const half8v*)&wpad[(wm * 32 + 16 + lr) * WCOLS + cc * 96 + ks * 32 + q * 8];
            half8v B0 = *(const half8v*)&Pl[(wn * 32 + lr) * S_ + ks * 32 + q * 8];
            half8v B1 = *(const half8v*)&Pl[(wn * 32 + 16 + lr) * S_ + ks * 32 + q * 8];
            a00 = __builtin_amdgcn_mfma_f32_16x16x32_f16(A0, B0, a00, 0, 0, 0);
            a01 = __builtin_amdgcn_mfma_f32_16x16x32_f16(A0, B1, a01, 0, 0, 0);
            a10 = __builtin_amdgcn_mfma_f32_16x16x32_f16(A1, B0, a10, 0, 0, 0);
            a11 = __builtin_amdgcn_mfma_f32_16x16x32_f16(A1, B1, a11, 0, 0, 0);
        }
    }

    // ---- epilogue ----
    const int pixc = hb * 64 + wn * 32 + lr;
#pragma unroll
    for (int r = 0; r < 4; r++) {
        int oc0 = wm * 32 + q * 4 + r;
        int oc1 = oc0 + 16;
        float* o0 = out + (((long)(b * OC_ + oc0)) << 14) + (ho << 7);
        float* o1 = out + (((long)(b * OC_ + oc1)) << 14) + (ho << 7);
        o0[pixc]      = a00[r] + bias[oc0];
        o0[pixc + 16] = a01[r] + bias[oc0];
        o1[pixc]      = a10[r] + bias[oc1];
        o1[pixc + 16] = a11[r] + bias[oc1];
    }
}

// ---------------------------------------------------------------------------
extern "C" void kernel_launch(void* const* d_in, const int* in_sizes, int n_in,
                              void* d_out, int out_size, void* d_ws, size_t ws_size,
                              hipStream_t stream) {
    const float* x  = (const float*)d_in[0];
    const float* wt = (const float*)d_in[1];
    const float* bi = (const float*)d_in[2];
    const float* ow = (const float*)d_in[3];
    const float* ob = (const float*)d_in[4];
    float* out = (float*)d_out;

    _Float16* wpad  = (_Float16*)d_ws;
    _Float16* w0pad = wpad + WPAD_HALFS;
    float*    zp    = (float*)((char*)d_ws + ZPAGE_BYTE);

    k0_prep<<<(OC_ * WCOLS + 32 * WCOLS + 255) / 256, 256, 0, stream>>>(wt, ow, wpad, w0pad, zp);
    k_fused<<<B_ * H_ * 2, 256, 0, stream>>>(x, wpad, w0pad, bi, ob, zp, out);
}